// Round 5
// baseline (64.119 us; speedup 1.0000x reference)
//
#include <hip/hip_runtime.h>
#include <stdint.h>

#define BTOT 8192
#define NSS  4096
#define LL   64
#define BT   32            // batches per workgroup
#define STT  32            // states per tile
#define NT   (NSS/STT)     // 128 state tiles total
#define NSPLIT 4           // state splits across blocks
#define TPS  (NT/NSPLIT)   // 32 tiles per split (8 per wave, 4 pairs)
#define JROWB 80           // padded LDS row bytes for J tile

typedef __bf16 bf16x8 __attribute__((ext_vector_type(8)));
typedef float  f32x4  __attribute__((ext_vector_type(4)));

static __device__ __forceinline__ unsigned short f2bf(float x){
  union { float f; uint32_t u; } v; v.f = x;
  uint32_t r = v.u + 0x7fffu + ((v.u >> 16) & 1u);
  return (unsigned short)(r >> 16);
}
static __device__ __forceinline__ float bf2f(unsigned short b){
  union { uint32_t u; float f; } v; v.u = ((uint32_t)b) << 16; return v.f;
}

// Build S in bf16 (row-major [NS][64]) and S^T in bf16 ([64][NS]) in workspace.
__global__ void prepack_kernel(const float* __restrict__ S,
                               unsigned short* __restrict__ Sb,
                               unsigned short* __restrict__ STb){
  int i = blockIdx.x * blockDim.x + threadIdx.x;
  Sb[i] = f2bf(S[i]);
  int l = i >> 12;                                  // i = l*4096 + s
  int s = i & (NSS - 1);
  STb[i] = f2bf(S[s * LL + l]);
}

__launch_bounds__(256, 4)
__global__ void fused_kernel(const float* __restrict__ f,
                             const unsigned short* __restrict__ Sb,
                             const unsigned short* __restrict__ STb,
                             float* __restrict__ numPart,   // [NSPLIT][BTOT][LL]
                             float* __restrict__ zPart){    // [NSPLIT][BTOT]
  const int tid  = threadIdx.x;
  const int w    = tid >> 6;
  const int lane = tid & 63;
  const int c16  = lane & 15;
  const int q4   = lane >> 4;
  const int bt   = blockIdx.x & 255;
  const int sp   = blockIdx.x >> 8;          // state split 0..3
  const int bb   = bt * BT;

  __shared__ unsigned char jraw[4][2][32 * JROWB]; // per-wave, per-stream J tiles
  __shared__ float nredQ[4][16 * 33];              // quarter-label cross-wave reduce
  __shared__ float zred[4][128];

  // ---- prologue: f B-fragments with hi/lo bf16 split (register-resident) ----
  bf16x8 fhi[2][2], flo[2][2];
  #pragma unroll
  for (int g = 0; g < 2; ++g){
    const float* frow = f + (size_t)(bb + g*16 + c16) * LL;
    #pragma unroll
    for (int kc = 0; kc < 2; ++kc){
      float vv[8];
      *(float4*)&vv[0] = *(const float4*)&frow[kc*32 + 8*q4];
      *(float4*)&vv[4] = *(const float4*)&frow[kc*32 + 8*q4 + 4];
      union { unsigned short u[8]; bf16x8 v; } H, Lo;
      #pragma unroll
      for (int j = 0; j < 8; ++j){
        unsigned short h = f2bf(vv[j]);
        H.u[j]  = h;
        Lo.u[j] = f2bf(vv[j] - bf2f(h));
      }
      fhi[g][kc] = H.v; flo[g][kc] = Lo.v;
    }
  }

  f32x4 acc2[4][2];
  #pragma unroll
  for (int lt = 0; lt < 4; ++lt)
    #pragma unroll
    for (int g = 0; g < 2; ++g) acc2[lt][g] = (f32x4){0.f,0.f,0.f,0.f};
  float zpart[2] = {0.f, 0.f};

  unsigned char* jbA = &jraw[w][0][0];
  unsigned char* jbB = &jraw[w][1][0];

  // ---- main loop: wave w owns 8 contiguous tiles, processed as 4 pairs ----
  const int tbase = sp * TPS + w * 8;
  for (int jp = 0; jp < 4; ++jp){
    const int sA = (tbase + 2*jp) * STT;
    const int sB = sA + STT;

    // issue all a1 loads for both streams (L2-resident Sb)
    bf16x8 a1A[2][2], a1B[2][2];
    #pragma unroll
    for (int ss = 0; ss < 2; ++ss)
      #pragma unroll
      for (int kc = 0; kc < 2; ++kc){
        a1A[ss][kc] = *(const bf16x8*)&Sb[(size_t)(sA + ss*16 + c16)*LL + kc*32 + 8*q4];
        a1B[ss][kc] = *(const bf16x8*)&Sb[(size_t)(sB + ss*16 + c16)*LL + kc*32 + 8*q4];
      }

    // GEMM1 both streams, interleaved (8 independent acc chains)
    f32x4 pA[2][2], pB[2][2];
    #pragma unroll
    for (int ss = 0; ss < 2; ++ss)
      #pragma unroll
      for (int g = 0; g < 2; ++g){
        f32x4 a = (f32x4){0.f,0.f,0.f,0.f};
        f32x4 b = (f32x4){0.f,0.f,0.f,0.f};
        #pragma unroll
        for (int kc = 0; kc < 2; ++kc){
          a = __builtin_amdgcn_mfma_f32_16x16x32_bf16(a1A[ss][kc], fhi[g][kc], a, 0,0,0);
          b = __builtin_amdgcn_mfma_f32_16x16x32_bf16(a1B[ss][kc], fhi[g][kc], b, 0,0,0);
          a = __builtin_amdgcn_mfma_f32_16x16x32_bf16(a1A[ss][kc], flo[g][kc], a, 0,0,0);
          b = __builtin_amdgcn_mfma_f32_16x16x32_bf16(a1B[ss][kc], flo[g][kc], b, 0,0,0);
        }
        pA[ss][g] = a; pB[ss][g] = b;
      }

    // issue a2 loads early (consumed at GEMM2 below; exp section hides L2 latency)
    bf16x8 a2A[4], a2B[4];
    #pragma unroll
    for (int lt = 0; lt < 4; ++lt){
      a2A[lt] = *(const bf16x8*)&STb[(size_t)(lt*16 + c16)*NSS + sA + 8*q4];
      a2B[lt] = *(const bf16x8*)&STb[(size_t)(lt*16 + c16)*NSS + sB + 8*q4];
    }

    // exp -> z -> pack bf16 -> per-stream LDS (streams interleaved for VALU/MFMA overlap)
    #pragma unroll
    for (int ss = 0; ss < 2; ++ss)
      #pragma unroll
      for (int g = 0; g < 2; ++g){
        int row = g*16 + c16;
        {
          float J0 = __expf(pA[ss][g][0]);
          float J1 = __expf(pA[ss][g][1]);
          float J2 = __expf(pA[ss][g][2]);
          float J3 = __expf(pA[ss][g][3]);
          zpart[g] += (J0 + J1) + (J2 + J3);
          uint32_t w0 = (uint32_t)f2bf(J0) | ((uint32_t)f2bf(J1) << 16);
          uint32_t w1 = (uint32_t)f2bf(J2) | ((uint32_t)f2bf(J3) << 16);
          *(uint2*)&jbA[row*JROWB + ss*32 + q4*8] = make_uint2(w0, w1);
        }
        {
          float J0 = __expf(pB[ss][g][0]);
          float J1 = __expf(pB[ss][g][1]);
          float J2 = __expf(pB[ss][g][2]);
          float J3 = __expf(pB[ss][g][3]);
          zpart[g] += (J0 + J1) + (J2 + J3);
          uint32_t w0 = (uint32_t)f2bf(J0) | ((uint32_t)f2bf(J1) << 16);
          uint32_t w1 = (uint32_t)f2bf(J2) | ((uint32_t)f2bf(J3) << 16);
          *(uint2*)&jbB[row*JROWB + ss*32 + q4*8] = make_uint2(w0, w1);
        }
      }

    // B-fragment reads of J (same-wave LDS RAW; compiler inserts lgkmcnt)
    bf16x8 b2A[2], b2B[2];
    #pragma unroll
    for (int g = 0; g < 2; ++g){
      int row = g*16 + c16;
      b2A[g] = *(const bf16x8*)&jbA[row*JROWB + q4*16];
      b2B[g] = *(const bf16x8*)&jbB[row*JROWB + q4*16];
    }

    // GEMM2: num[l,b] += S^T @ J, both streams
    #pragma unroll
    for (int lt = 0; lt < 4; ++lt)
      #pragma unroll
      for (int g = 0; g < 2; ++g){
        acc2[lt][g] = __builtin_amdgcn_mfma_f32_16x16x32_bf16(a2A[lt], b2A[g], acc2[lt][g], 0,0,0);
        acc2[lt][g] = __builtin_amdgcn_mfma_f32_16x16x32_bf16(a2B[lt], b2B[g], acc2[lt][g], 0,0,0);
      }
  }

  // ---- epilogue: z reduce, then 4 quarter-label stages through small LDS buffer ----
  float* numOut = numPart + (size_t)sp * BTOT * LL + (size_t)bb * LL;
  zred[w][q4*32 + c16]      = zpart[0];
  zred[w][q4*32 + 16 + c16] = zpart[1];

  #pragma unroll
  for (int lt = 0; lt < 4; ++lt){
    #pragma unroll
    for (int g = 0; g < 2; ++g)
      #pragma unroll
      for (int jj = 0; jj < 4; ++jj)
        nredQ[w][(q4*4 + jj)*33 + g*16 + c16] = acc2[lt][g][jj];
    __syncthreads();
    if (lt == 0 && tid < BT){
      float zz = 0.f;
      #pragma unroll
      for (int ww = 0; ww < 4; ++ww)
        #pragma unroll
        for (int qq = 0; qq < 4; ++qq) zz += zred[ww][qq*32 + tid];
      zPart[(size_t)sp * BTOT + bb + tid] = zz;
    }
    #pragma unroll
    for (int it = 0; it < 2; ++it){
      int idx = it*256 + tid;          // 0..511: 32 batches x 16 labels
      int b = idx >> 4, l = idx & 15;
      float v = (nredQ[0][l*33+b] + nredQ[1][l*33+b]) + (nredQ[2][l*33+b] + nredQ[3][l*33+b]);
      numOut[(size_t)b*LL + lt*16 + l] = v;
    }
    __syncthreads();
  }
}

// finalize: sum split partials, p = num/z, BCE, per-block loss partials
__global__ void finalize_kernel(const float* __restrict__ numPart,
                                const float* __restrict__ zPart,
                                const float* __restrict__ y,
                                const float* __restrict__ mask,
                                float* __restrict__ out,     // [1 + BTOT*LL]
                                float* __restrict__ parts){  // [2048]
  int tid = threadIdx.x;
  int idx = blockIdx.x * 256 + tid;      // 0 .. BTOT*LL-1
  int b = idx >> 6;
  float num = 0.f, z = 0.f;
  #pragma unroll
  for (int sp = 0; sp < NSPLIT; ++sp){
    num += numPart[(size_t)sp * BTOT * LL + idx];
    z   += zPart[(size_t)sp * BTOT + b];
  }
  float p = fminf(num / z, 1.0f);
  out[1 + idx] = p;
  float lg = fmaxf(__logf(p), -100.f);
  float l1 = fmaxf(log1pf(-p), -100.f);
  float yv = y[idx], mv = mask[idx];
  float lsum = -(yv*lg + (1.f - yv)*l1) * mv;
  #pragma unroll
  for (int off = 32; off; off >>= 1) lsum += __shfl_down(lsum, off);
  __shared__ float wred[4];
  int w = tid >> 6, lane = tid & 63;
  if (lane == 0) wred[w] = lsum;
  __syncthreads();
  if (tid == 0) parts[blockIdx.x] = (wred[0] + wred[1]) + (wred[2] + wred[3]);
}

__global__ void loss_kernel(const float* __restrict__ parts, float* __restrict__ out){
  float v = 0.f;
  #pragma unroll
  for (int i = 0; i < 8; ++i) v += parts[threadIdx.x + 256*i];
  #pragma unroll
  for (int off = 32; off; off >>= 1) v += __shfl_down(v, off);
  __shared__ float sred[4];
  int w = threadIdx.x >> 6, lane = threadIdx.x & 63;
  if (lane == 0) sred[w] = v;
  __syncthreads();
  if (threadIdx.x == 0)
    out[0] = ((sred[0] + sred[1]) + (sred[2] + sred[3])) * (1.0f / ((float)BTOT * (float)LL));
}

extern "C" void kernel_launch(void* const* d_in, const int* in_sizes, int n_in,
                              void* d_out, int out_size, void* d_ws, size_t ws_size,
                              hipStream_t stream){
  const float* f = (const float*)d_in[0];
  const float* y = (const float*)d_in[1];
  const float* m = (const float*)d_in[2];
  const float* S = (const float*)d_in[3];
  float* out = (float*)d_out;

  unsigned short* Sb  = (unsigned short*)d_ws;                 // 512 KB
  unsigned short* STb = Sb + (size_t)NSS * LL;                 // 512 KB
  char* p = (char*)d_ws + (size_t)2 * NSS * LL * sizeof(unsigned short);
  float* numPart = (float*)p;  p += (size_t)NSPLIT * BTOT * LL * sizeof(float);  // 8 MB
  float* zPart   = (float*)p;  p += (size_t)NSPLIT * BTOT * sizeof(float);       // 128 KB
  float* parts   = (float*)p;                                                    // 8 KB

  prepack_kernel<<<(NSS*LL)/256, 256, 0, stream>>>(S, Sb, STb);
  fused_kernel<<<256 * NSPLIT, 256, 0, stream>>>(f, Sb, STb, numPart, zPart);
  finalize_kernel<<<(BTOT*LL)/256, 256, 0, stream>>>(numPart, zPart, y, m, out, parts);
  loss_kernel<<<1, 256, 0, stream>>>(parts, out);
}

// Round 6
// 35.884 us; speedup vs baseline: 1.7869x; 1.7869x over previous
//
#include <hip/hip_runtime.h>
#include <stdint.h>

#define BTOT 8192
#define NSS  4096
#define LL   64
#define BT   32            // batches per workgroup
#define STT  32            // states per tile
#define NT   (NSS/STT)     // 128 state tiles total
#define NSPLIT 4           // state splits across blocks
#define TPS  (NT/NSPLIT)   // 32 tiles per split (8 per wave)
#define JROWB 80           // padded LDS row bytes for J tile

typedef __bf16    bf16x8 __attribute__((ext_vector_type(8)));
typedef _Float16  f16x8  __attribute__((ext_vector_type(8)));
typedef float     f32x4  __attribute__((ext_vector_type(4)));

static __device__ __forceinline__ unsigned short f2bf(float x){
  union { float f; uint32_t u; } v; v.f = x;
  uint32_t r = v.u + 0x7fffu + ((v.u >> 16) & 1u);
  return (unsigned short)(r >> 16);
}

// Pack S into MFMA-fragment order:
//  Sp  (f16):  GEMM1 A-frags. item (t, frag=ss*2+kc, lane): j -> S[t*32+ss*16+(lane&15)][kc*32+(lane>>4)*8+j]
//  STp (bf16): GEMM2 A-frags. item (t, lt, lane):          j -> S[t*32+(lane>>4)*8+j][lt*16+(lane&15)]
// Every main-loop operand load becomes one coalesced 1KB dwordx4 per wave.
__global__ void prepack_kernel(const float* __restrict__ S,
                               _Float16* __restrict__ Sp,
                               unsigned short* __restrict__ STp){
  const int t = blockIdx.x;
  const int sbase = t * STT;
  #pragma unroll
  for (int rep = 0; rep < 2; ++rep){
    int item = rep * 256 + threadIdx.x;    // 0..511
    int frag = item >> 6;                  // 0..7
    int lane = item & 63;
    int c16 = lane & 15, q4 = lane >> 4;
    if (frag < 4){
      int ss = frag >> 1, kc = frag & 1;
      const float* row = S + (size_t)(sbase + ss*16 + c16)*LL + kc*32 + q4*8;
      f16x8 h;
      #pragma unroll
      for (int j = 0; j < 8; ++j) h[j] = (_Float16)row[j];   // 0/1 exact
      *(f16x8*)&Sp[((size_t)(t*4 + frag)*64 + lane)*8] = h;
    } else {
      int lt = frag - 4;
      int l  = lt*16 + c16;
      int s0 = sbase + q4*8;
      union { unsigned short u[8]; bf16x8 v; } H;
      #pragma unroll
      for (int j = 0; j < 8; ++j) H.u[j] = f2bf(S[(size_t)(s0 + j)*LL + l]);  // 0/1 exact
      *(bf16x8*)&STp[((size_t)(t*4 + lt)*64 + lane)*8] = H.v;
    }
  }
}

__launch_bounds__(256, 4)
__global__ void fused_kernel(const float* __restrict__ f,
                             const _Float16* __restrict__ Sp,
                             const unsigned short* __restrict__ STp,
                             float* __restrict__ numPart,   // [NSPLIT][BTOT][LL]
                             float* __restrict__ zPart){    // [NSPLIT][BTOT]
  const int tid  = threadIdx.x;
  const int w    = tid >> 6;
  const int lane = tid & 63;
  const int c16  = lane & 15;
  const int q4   = lane >> 4;
  const int bt   = blockIdx.x & 255;
  const int sp   = blockIdx.x >> 8;          // state split 0..3
  const int bb   = bt * BT;

  __shared__ unsigned char jraw[4][32 * JROWB]; // per-wave J tile [32 batch rows][32 states bf16]
  __shared__ float nredQ[4][16 * 33];           // quarter-label cross-wave reduce
  __shared__ float zred[4][128];

  // ---- prologue: f B-fragments in f16 (register-resident) ----
  // B-frag layout: col = lane&15 (batch), k = (lane>>4)*8 + j (label)
  f16x8 fB[2][2];
  #pragma unroll
  for (int g = 0; g < 2; ++g){
    const float* frow = f + (size_t)(bb + g*16 + c16) * LL;
    #pragma unroll
    for (int kc = 0; kc < 2; ++kc){
      float vv[8];
      *(float4*)&vv[0] = *(const float4*)&frow[kc*32 + 8*q4];
      *(float4*)&vv[4] = *(const float4*)&frow[kc*32 + 8*q4 + 4];
      f16x8 h;
      #pragma unroll
      for (int j = 0; j < 8; ++j) h[j] = (_Float16)vv[j];
      fB[g][kc] = h;
    }
  }

  f32x4 acc2[4][2];
  #pragma unroll
  for (int lt = 0; lt < 4; ++lt)
    #pragma unroll
    for (int g = 0; g < 2; ++g) acc2[lt][g] = (f32x4){0.f,0.f,0.f,0.f};
  float zpart[2] = {0.f, 0.f};

  unsigned char* jb = jraw[w];

#define LOAD_A1(TT, A1) do {                                              \
    const _Float16* ps_ = Sp + ((size_t)((TT)*4)*64 + lane)*8;            \
    _Pragma("unroll")                                                     \
    for (int k_ = 0; k_ < 4; ++k_)                                        \
      (A1)[k_] = *(const f16x8*)(ps_ + (size_t)k_*64*8);                  \
  } while(0)

#define COMPUTE_TILE(TT, A1) do {                                         \
    /* a2 issued first: L2 latency hides under GEMM1+exp+LDS */           \
    bf16x8 a2_[4];                                                        \
    const unsigned short* pt_ = STp + ((size_t)((TT)*4)*64 + lane)*8;     \
    _Pragma("unroll")                                                     \
    for (int lt_ = 0; lt_ < 4; ++lt_)                                     \
      a2_[lt_] = *(const bf16x8*)(pt_ + (size_t)lt_*64*8);                \
    /* GEMM1: potential tile (f16) */                                     \
    f32x4 p_[2][2];                                                       \
    _Pragma("unroll")                                                     \
    for (int ss_ = 0; ss_ < 2; ++ss_)                                     \
      _Pragma("unroll")                                                   \
      for (int g_ = 0; g_ < 2; ++g_){                                     \
        f32x4 a_ = (f32x4){0.f,0.f,0.f,0.f};                              \
        a_ = __builtin_amdgcn_mfma_f32_16x16x32_f16((A1)[ss_*2+0], fB[g_][0], a_, 0,0,0); \
        a_ = __builtin_amdgcn_mfma_f32_16x16x32_f16((A1)[ss_*2+1], fB[g_][1], a_, 0,0,0); \
        p_[ss_][g_] = a_;                                                 \
      }                                                                   \
    /* exp -> z -> pack bf16 -> per-wave LDS */                           \
    _Pragma("unroll")                                                     \
    for (int ss_ = 0; ss_ < 2; ++ss_)                                     \
      _Pragma("unroll")                                                   \
      for (int g_ = 0; g_ < 2; ++g_){                                     \
        float J0 = __expf(p_[ss_][g_][0]);                                \
        float J1 = __expf(p_[ss_][g_][1]);                                \
        float J2 = __expf(p_[ss_][g_][2]);                                \
        float J3 = __expf(p_[ss_][g_][3]);                                \
        zpart[g_] += (J0 + J1) + (J2 + J3);                               \
        union { __bf16 h[4]; uint2 u2; } P_;                              \
        P_.h[0] = (__bf16)J0; P_.h[1] = (__bf16)J1;                       \
        P_.h[2] = (__bf16)J2; P_.h[3] = (__bf16)J3;                       \
        *(uint2*)&jb[(g_*16 + c16)*JROWB + ss_*32 + q4*8] = P_.u2;        \
      }                                                                   \
    /* B-frag reads of J (same-wave LDS RAW) */                           \
    bf16x8 b2_[2];                                                        \
    _Pragma("unroll")                                                     \
    for (int g_ = 0; g_ < 2; ++g_)                                        \
      b2_[g_] = *(const bf16x8*)&jb[(g_*16 + c16)*JROWB + q4*16];         \
    /* GEMM2: num += S^T @ J (bf16) */                                    \
    _Pragma("unroll")                                                     \
    for (int lt_ = 0; lt_ < 4; ++lt_)                                     \
      _Pragma("unroll")                                                   \
      for (int g_ = 0; g_ < 2; ++g_)                                      \
        acc2[lt_][g_] = __builtin_amdgcn_mfma_f32_16x16x32_bf16(a2_[lt_], b2_[g_], acc2[lt_][g_], 0,0,0); \
  } while(0)

  // ---- main loop: 8 tiles per wave, named-buffer 1-deep a1 pipeline ----
  const int tb = sp * TPS + w * 8;
  f16x8 a1A[4], a1B[4];
  LOAD_A1(tb+0, a1A);
  LOAD_A1(tb+1, a1B);  COMPUTE_TILE(tb+0, a1A);
  LOAD_A1(tb+2, a1A);  COMPUTE_TILE(tb+1, a1B);
  LOAD_A1(tb+3, a1B);  COMPUTE_TILE(tb+2, a1A);
  LOAD_A1(tb+4, a1A);  COMPUTE_TILE(tb+3, a1B);
  LOAD_A1(tb+5, a1B);  COMPUTE_TILE(tb+4, a1A);
  LOAD_A1(tb+6, a1A);  COMPUTE_TILE(tb+5, a1B);
  LOAD_A1(tb+7, a1B);  COMPUTE_TILE(tb+6, a1A);
  COMPUTE_TILE(tb+7, a1B);

#undef LOAD_A1
#undef COMPUTE_TILE

  // ---- epilogue: z reduce, then 4 quarter-label stages through small LDS buffer ----
  float* numOut = numPart + (size_t)sp * BTOT * LL + (size_t)bb * LL;
  zred[w][q4*32 + c16]      = zpart[0];
  zred[w][q4*32 + 16 + c16] = zpart[1];

  #pragma unroll
  for (int lt = 0; lt < 4; ++lt){
    #pragma unroll
    for (int g = 0; g < 2; ++g)
      #pragma unroll
      for (int jj = 0; jj < 4; ++jj)
        nredQ[w][(q4*4 + jj)*33 + g*16 + c16] = acc2[lt][g][jj];
    __syncthreads();
    if (lt == 0 && tid < BT){
      float zz = 0.f;
      #pragma unroll
      for (int ww = 0; ww < 4; ++ww)
        #pragma unroll
        for (int qq = 0; qq < 4; ++qq) zz += zred[ww][qq*32 + tid];
      zPart[(size_t)sp * BTOT + bb + tid] = zz;
    }
    #pragma unroll
    for (int it = 0; it < 2; ++it){
      int idx = it*256 + tid;          // 0..511: 32 batches x 16 labels
      int b = idx >> 4, l = idx & 15;
      float v = (nredQ[0][l*33+b] + nredQ[1][l*33+b]) + (nredQ[2][l*33+b] + nredQ[3][l*33+b]);
      numOut[(size_t)b*LL + lt*16 + l] = v;
    }
    __syncthreads();
  }
}

// finalize: sum split partials, p = num/z, BCE, per-block loss partials
__global__ void finalize_kernel(const float* __restrict__ numPart,
                                const float* __restrict__ zPart,
                                const float* __restrict__ y,
                                const float* __restrict__ mask,
                                float* __restrict__ out,     // [1 + BTOT*LL]
                                float* __restrict__ parts){  // [2048]
  int tid = threadIdx.x;
  int idx = blockIdx.x * 256 + tid;      // 0 .. BTOT*LL-1
  int b = idx >> 6;
  float num = 0.f, z = 0.f;
  #pragma unroll
  for (int sp = 0; sp < NSPLIT; ++sp){
    num += numPart[(size_t)sp * BTOT * LL + idx];
    z   += zPart[(size_t)sp * BTOT + b];
  }
  float p = fminf(num / z, 1.0f);
  out[1 + idx] = p;
  float lg = fmaxf(__logf(p), -100.f);
  float l1 = fmaxf(log1pf(-p), -100.f);
  float yv = y[idx], mv = mask[idx];
  float lsum = -(yv*lg + (1.f - yv)*l1) * mv;
  #pragma unroll
  for (int off = 32; off; off >>= 1) lsum += __shfl_down(lsum, off);
  __shared__ float wred[4];
  int w = tid >> 6, lane = tid & 63;
  if (lane == 0) wred[w] = lsum;
  __syncthreads();
  if (tid == 0) parts[blockIdx.x] = (wred[0] + wred[1]) + (wred[2] + wred[3]);
}

__global__ void loss_kernel(const float* __restrict__ parts, float* __restrict__ out){
  float v = 0.f;
  #pragma unroll
  for (int i = 0; i < 8; ++i) v += parts[threadIdx.x + 256*i];
  #pragma unroll
  for (int off = 32; off; off >>= 1) v += __shfl_down(v, off);
  __shared__ float sred[4];
  int w = threadIdx.x >> 6, lane = threadIdx.x & 63;
  if (lane == 0) sred[w] = v;
  __syncthreads();
  if (threadIdx.x == 0)
    out[0] = ((sred[0] + sred[1]) + (sred[2] + sred[3])) * (1.0f / ((float)BTOT * (float)LL));
}

extern "C" void kernel_launch(void* const* d_in, const int* in_sizes, int n_in,
                              void* d_out, int out_size, void* d_ws, size_t ws_size,
                              hipStream_t stream){
  const float* f = (const float*)d_in[0];
  const float* y = (const float*)d_in[1];
  const float* m = (const float*)d_in[2];
  const float* S = (const float*)d_in[3];
  float* out = (float*)d_out;

  _Float16* Sp        = (_Float16*)d_ws;                               // 512 KB
  unsigned short* STp = (unsigned short*)(Sp + (size_t)NT*4*64*8);     // 512 KB
  char* p = (char*)d_ws + (size_t)2 * NT * 4 * 64 * 8 * 2;
  float* numPart = (float*)p;  p += (size_t)NSPLIT * BTOT * LL * sizeof(float);  // 8 MB
  float* zPart   = (float*)p;  p += (size_t)NSPLIT * BTOT * sizeof(float);       // 128 KB
  float* parts   = (float*)p;                                                    // 8 KB

  prepack_kernel<<<NT, 256, 0, stream>>>(S, Sp, STp);
  fused_kernel<<<256 * NSPLIT, 256, 0, stream>>>(f, Sp, STp, numPart, zPart);
  finalize_kernel<<<(BTOT*LL)/256, 256, 0, stream>>>(numPart, zPart, y, m, out, parts);
  loss_kernel<<<1, 256, 0, stream>>>(parts, out);
}

// Round 7
// 35.753 us; speedup vs baseline: 1.7934x; 1.0036x over previous
//
#include <hip/hip_runtime.h>
#include <stdint.h>

#define BTOT 8192
#define NSS  4096
#define LL   64
#define BT   32            // batches per workgroup
#define STT  32            // states per tile
#define NT   (NSS/STT)     // 128 state tiles total
#define NSPLIT 4           // state splits across blocks
#define TPS  (NT/NSPLIT)   // 32 tiles per split (8 per wave)
#define JROWB 80           // padded LDS row bytes for J tile
#define JBUFB (32 * JROWB) // one J buffer: 2560 B

typedef __bf16    bf16x8 __attribute__((ext_vector_type(8)));
typedef _Float16  f16x8  __attribute__((ext_vector_type(8)));
typedef float     f32x4  __attribute__((ext_vector_type(4)));

static __device__ __forceinline__ unsigned short f2bf(float x){
  union { float f; uint32_t u; } v; v.f = x;
  uint32_t r = v.u + 0x7fffu + ((v.u >> 16) & 1u);
  return (unsigned short)(r >> 16);
}

// Pack S into MFMA-fragment order (same as round 6):
//  Sp  (f16):  GEMM1 A-frags. item (t, frag=ss*2+kc, lane): j -> S[t*32+ss*16+(lane&15)][kc*32+(lane>>4)*8+j]
//  STp (bf16): GEMM2 A-frags. item (t, lt, lane):          j -> S[t*32+(lane>>4)*8+j][lt*16+(lane&15)]
__global__ void prepack_kernel(const float* __restrict__ S,
                               _Float16* __restrict__ Sp,
                               unsigned short* __restrict__ STp){
  const int t = blockIdx.x;
  const int sbase = t * STT;
  #pragma unroll
  for (int rep = 0; rep < 2; ++rep){
    int item = rep * 256 + threadIdx.x;    // 0..511
    int frag = item >> 6;                  // 0..7
    int lane = item & 63;
    int c16 = lane & 15, q4 = lane >> 4;
    if (frag < 4){
      int ss = frag >> 1, kc = frag & 1;
      const float* row = S + (size_t)(sbase + ss*16 + c16)*LL + kc*32 + q4*8;
      f16x8 h;
      #pragma unroll
      for (int j = 0; j < 8; ++j) h[j] = (_Float16)row[j];   // 0/1 exact
      *(f16x8*)&Sp[((size_t)(t*4 + frag)*64 + lane)*8] = h;
    } else {
      int lt = frag - 4;
      int l  = lt*16 + c16;
      int s0 = sbase + q4*8;
      union { unsigned short u[8]; bf16x8 v; } H;
      #pragma unroll
      for (int j = 0; j < 8; ++j) H.u[j] = f2bf(S[(size_t)(s0 + j)*LL + l]);  // 0/1 exact
      *(bf16x8*)&STp[((size_t)(t*4 + lt)*64 + lane)*8] = H.v;
    }
  }
}

__launch_bounds__(256, 4)
__global__ void fused_kernel(const float* __restrict__ f,
                             const _Float16* __restrict__ Sp,
                             const unsigned short* __restrict__ STp,
                             float* __restrict__ numPart,   // [NSPLIT][BTOT][LL]
                             float* __restrict__ zPart){    // [NSPLIT][BTOT]
  const int tid  = threadIdx.x;
  const int w    = tid >> 6;
  const int lane = tid & 63;
  const int c16  = lane & 15;
  const int q4   = lane >> 4;
  const int bt   = blockIdx.x & 255;
  const int sp   = blockIdx.x >> 8;          // state split 0..3
  const int bb   = bt * BT;

  // aliased LDS: main loop uses J double-buffers; epilogue (after barrier) reuses
  // the same bytes for the cross-wave reduce buffers.
  __shared__ unsigned char smem[4 * 2 * JBUFB];            // 20480 B
  unsigned char* jraw = smem + w * 2 * JBUFB;              // this wave's 2 J buffers
  float (*nredQ)[16*33] = (float (*)[16*33])smem;          // [4][528] = 8448 B
  float (*zred)[128]    = (float (*)[128])(smem + 4*528*4);// [4][128] = 2048 B

  // ---- prologue: f B-fragments in f16 (register-resident) ----
  // B-frag layout: col = lane&15 (batch), k = (lane>>4)*8 + j (label)
  f16x8 fB[2][2];
  #pragma unroll
  for (int g = 0; g < 2; ++g){
    const float* frow = f + (size_t)(bb + g*16 + c16) * LL;
    #pragma unroll
    for (int kc = 0; kc < 2; ++kc){
      float vv[8];
      *(float4*)&vv[0] = *(const float4*)&frow[kc*32 + 8*q4];
      *(float4*)&vv[4] = *(const float4*)&frow[kc*32 + 8*q4 + 4];
      f16x8 h;
      #pragma unroll
      for (int j = 0; j < 8; ++j) h[j] = (_Float16)vv[j];
      fB[g][kc] = h;
    }
  }

  f32x4 acc2[4][2];
  #pragma unroll
  for (int lt = 0; lt < 4; ++lt)
    #pragma unroll
    for (int g = 0; g < 2; ++g) acc2[lt][g] = (f32x4){0.f,0.f,0.f,0.f};
  float zpart[2] = {0.f, 0.f};

  // ---- software-pipelined main loop over this wave's 8 tiles ----
  // iter t: GEMM1(t) | prefetch a1(t+1) | exp/pack(t)->jb[t&1] |
  //         GEMM2(t-1) from jb[(t-1)&1] + a2[(t-1)&1] | prefetch a2(t)->a2[t&1]
  const int tb = sp * TPS + w * 8;
  f16x8  a1[2][4];
  bf16x8 a2[2][4];
  {
    const _Float16* ps = Sp + ((size_t)(tb*4)*64 + lane)*8;
    #pragma unroll
    for (int k = 0; k < 4; ++k) a1[0][k] = *(const f16x8*)(ps + (size_t)k*64*8);
  }

  #pragma unroll
  for (int t = 0; t < 8; ++t){
    const int cur = t & 1, nxt = cur ^ 1;
    unsigned char* jcur = jraw + cur * JBUFB;
    unsigned char* jprv = jraw + nxt * JBUFB;

    // GEMM1: potential tile t (f16)
    f32x4 p_[2][2];
    #pragma unroll
    for (int ss = 0; ss < 2; ++ss)
      #pragma unroll
      for (int g = 0; g < 2; ++g){
        f32x4 a = (f32x4){0.f,0.f,0.f,0.f};
        a = __builtin_amdgcn_mfma_f32_16x16x32_f16(a1[cur][ss*2+0], fB[g][0], a, 0,0,0);
        a = __builtin_amdgcn_mfma_f32_16x16x32_f16(a1[cur][ss*2+1], fB[g][1], a, 0,0,0);
        p_[ss][g] = a;
      }

    // prefetch a1 for tile t+1 (consumed next iteration's GEMM1)
    if (t < 7){
      const _Float16* ps = Sp + ((size_t)((tb+t+1)*4)*64 + lane)*8;
      #pragma unroll
      for (int k = 0; k < 4; ++k) a1[nxt][k] = *(const f16x8*)(ps + (size_t)k*64*8);
    }

    // exp -> z -> pack bf16 -> jb[cur]
    #pragma unroll
    for (int ss = 0; ss < 2; ++ss)
      #pragma unroll
      for (int g = 0; g < 2; ++g){
        float J0 = __expf(p_[ss][g][0]);
        float J1 = __expf(p_[ss][g][1]);
        float J2 = __expf(p_[ss][g][2]);
        float J3 = __expf(p_[ss][g][3]);
        zpart[g] += (J0 + J1) + (J2 + J3);
        union { __bf16 h[4]; uint2 u2; } P_;
        P_.h[0] = (__bf16)J0; P_.h[1] = (__bf16)J1;
        P_.h[2] = (__bf16)J2; P_.h[3] = (__bf16)J3;
        *(uint2*)&jcur[(g*16 + c16)*JROWB + ss*32 + q4*8] = P_.u2;
      }

    // GEMM2 for tile t-1 (J written a full iteration ago -> RAW covered)
    if (t > 0){
      bf16x8 b2[2];
      #pragma unroll
      for (int g = 0; g < 2; ++g)
        b2[g] = *(const bf16x8*)&jprv[(g*16 + c16)*JROWB + q4*16];
      #pragma unroll
      for (int lt = 0; lt < 4; ++lt)
        #pragma unroll
        for (int g = 0; g < 2; ++g)
          acc2[lt][g] = __builtin_amdgcn_mfma_f32_16x16x32_bf16(a2[nxt][lt], b2[g], acc2[lt][g], 0,0,0);
    }

    // prefetch a2 for tile t (consumed next iteration / drain)
    {
      const unsigned short* pt = STp + ((size_t)((tb+t)*4)*64 + lane)*8;
      #pragma unroll
      for (int lt = 0; lt < 4; ++lt)
        a2[cur][lt] = *(const bf16x8*)(pt + (size_t)lt*64*8);
    }
  }

  // drain: GEMM2 for tile 7 (jb[1], a2[1])
  {
    unsigned char* jprv = jraw + 1 * JBUFB;
    bf16x8 b2[2];
    #pragma unroll
    for (int g = 0; g < 2; ++g)
      b2[g] = *(const bf16x8*)&jprv[(g*16 + c16)*JROWB + q4*16];
    #pragma unroll
    for (int lt = 0; lt < 4; ++lt)
      #pragma unroll
      for (int g = 0; g < 2; ++g)
        acc2[lt][g] = __builtin_amdgcn_mfma_f32_16x16x32_bf16(a2[1][lt], b2[g], acc2[lt][g], 0,0,0);
  }

  __syncthreads();   // all waves done with J buffers; smem is reused below

  // ---- epilogue: z reduce, then 4 quarter-label stages through aliased LDS ----
  float* numOut = numPart + (size_t)sp * BTOT * LL + (size_t)bb * LL;
  zred[w][q4*32 + c16]      = zpart[0];
  zred[w][q4*32 + 16 + c16] = zpart[1];

  #pragma unroll
  for (int lt = 0; lt < 4; ++lt){
    #pragma unroll
    for (int g = 0; g < 2; ++g)
      #pragma unroll
      for (int jj = 0; jj < 4; ++jj)
        nredQ[w][(q4*4 + jj)*33 + g*16 + c16] = acc2[lt][g][jj];
    __syncthreads();
    if (lt == 0 && tid < BT){
      float zz = 0.f;
      #pragma unroll
      for (int ww = 0; ww < 4; ++ww)
        #pragma unroll
        for (int qq = 0; qq < 4; ++qq) zz += zred[ww][qq*32 + tid];
      zPart[(size_t)sp * BTOT + bb + tid] = zz;
    }
    #pragma unroll
    for (int it = 0; it < 2; ++it){
      int idx = it*256 + tid;          // 0..511: 32 batches x 16 labels
      int b = idx >> 4, l = idx & 15;
      float v = (nredQ[0][l*33+b] + nredQ[1][l*33+b]) + (nredQ[2][l*33+b] + nredQ[3][l*33+b]);
      numOut[(size_t)b*LL + lt*16 + l] = v;
    }
    __syncthreads();
  }
}

// finalize: sum split partials, p = num/z, BCE, per-block loss partials
__global__ void finalize_kernel(const float* __restrict__ numPart,
                                const float* __restrict__ zPart,
                                const float* __restrict__ y,
                                const float* __restrict__ mask,
                                float* __restrict__ out,     // [1 + BTOT*LL]
                                float* __restrict__ parts){  // [2048]
  int tid = threadIdx.x;
  int idx = blockIdx.x * 256 + tid;      // 0 .. BTOT*LL-1
  int b = idx >> 6;
  float num = 0.f, z = 0.f;
  #pragma unroll
  for (int sp = 0; sp < NSPLIT; ++sp){
    num += numPart[(size_t)sp * BTOT * LL + idx];
    z   += zPart[(size_t)sp * BTOT + b];
  }
  float p = fminf(num / z, 1.0f);
  out[1 + idx] = p;
  float lg = fmaxf(__logf(p), -100.f);
  float l1 = fmaxf(log1pf(-p), -100.f);
  float yv = y[idx], mv = mask[idx];
  float lsum = -(yv*lg + (1.f - yv)*l1) * mv;
  #pragma unroll
  for (int off = 32; off; off >>= 1) lsum += __shfl_down(lsum, off);
  __shared__ float wred[4];
  int w = tid >> 6, lane = tid & 63;
  if (lane == 0) wred[w] = lsum;
  __syncthreads();
  if (tid == 0) parts[blockIdx.x] = (wred[0] + wred[1]) + (wred[2] + wred[3]);
}

__global__ void loss_kernel(const float* __restrict__ parts, float* __restrict__ out){
  float v = 0.f;
  #pragma unroll
  for (int i = 0; i < 8; ++i) v += parts[threadIdx.x + 256*i];
  #pragma unroll
  for (int off = 32; off; off >>= 1) v += __shfl_down(v, off);
  __shared__ float sred[4];
  int w = threadIdx.x >> 6, lane = threadIdx.x & 63;
  if (lane == 0) sred[w] = v;
  __syncthreads();
  if (threadIdx.x == 0)
    out[0] = ((sred[0] + sred[1]) + (sred[2] + sred[3])) * (1.0f / ((float)BTOT * (float)LL));
}

extern "C" void kernel_launch(void* const* d_in, const int* in_sizes, int n_in,
                              void* d_out, int out_size, void* d_ws, size_t ws_size,
                              hipStream_t stream){
  const float* f = (const float*)d_in[0];
  const float* y = (const float*)d_in[1];
  const float* m = (const float*)d_in[2];
  const float* S = (const float*)d_in[3];
  float* out = (float*)d_out;

  _Float16* Sp        = (_Float16*)d_ws;                               // 512 KB
  unsigned short* STp = (unsigned short*)(Sp + (size_t)NT*4*64*8);     // 512 KB
  char* p = (char*)d_ws + (size_t)2 * NT * 4 * 64 * 8 * 2;
  float* numPart = (float*)p;  p += (size_t)NSPLIT * BTOT * LL * sizeof(float);  // 8 MB
  float* zPart   = (float*)p;  p += (size_t)NSPLIT * BTOT * sizeof(float);       // 128 KB
  float* parts   = (float*)p;                                                    // 8 KB

  prepack_kernel<<<NT, 256, 0, stream>>>(S, Sp, STp);
  fused_kernel<<<256 * NSPLIT, 256, 0, stream>>>(f, Sp, STp, numPart, zPart);
  finalize_kernel<<<(BTOT*LL)/256, 256, 0, stream>>>(numPart, zPart, y, m, out, parts);
  loss_kernel<<<1, 256, 0, stream>>>(parts, out);
}